// Round 8
// baseline (11204.794 us; speedup 1.0000x reference)
//
#include <hip/hip_runtime.h>
#include <hip/hip_bf16.h>
#include <stdint.h>

#define NN 100000   // nodes
#define DD 128      // input dim
#define OO 128      // output dim
#define NS 8        // relations
#define NB 4        // bases

#define BROWS 128   // rows per bucket (tile = 128x128 f32 = 64KB LDS)
#define NBUCK 782   // ceil(NN/BROWS)
#define SDEPTH 8    // LDS staging depth per bucket (flush = 8 entries = 64B)
#define BCAP 2432   // per-bucket capacity: mean 2046 (E/NBUCK) + ~8.5 sigma
#define CPAD 16     // cursor padding (ints) = 64B/counter

typedef __attribute__((ext_vector_type(8))) short short8;
typedef __attribute__((ext_vector_type(4))) float f32x4;

__device__ __forceinline__ float bf2f(uint16_t u){
  union { uint32_t i; float f; } x; x.i = ((uint32_t)u) << 16; return x.f;
}
__device__ __forceinline__ uint16_t f2bf(float f){
  union { float f; uint32_t i; } x; x.f = f;
  uint32_t r = (x.i + 0x7FFFu + ((x.i >> 16) & 1u)) >> 16;  // RNE
  return (uint16_t)r;
}

// ---- cast features f32 -> bf16 ----
__global__ void cast_bf16_kernel(const float* __restrict__ in, uint16_t* __restrict__ out, int n4){
  int i = blockIdx.x * blockDim.x + threadIdx.x;
  if (i < n4){
    float4 v = ((const float4*)in)[i];
    ushort4 o;
    o.x = f2bf(v.x); o.y = f2bf(v.y); o.z = f2bf(v.z); o.w = f2bf(v.w);
    ((ushort4*)out)[i] = o;
  }
}

// ---- effective per-relation weight, TRANSPOSED: Vt[s][o][d] = M_s[d][o] ----
// M_s[d,o] = sum_b W_comp[d&7, b] * W[b*128 + s*16 + (d>>3), o]  (validated R1-R6)
__global__ void vt_kernel(const float* __restrict__ W, const float* __restrict__ Wc,
                          uint16_t* __restrict__ Vt){
  int d  = threadIdx.x;
  int so = blockIdx.x;
  int s = so >> 7, o = so & 127;
  int wrow = s * 16 + (d >> 3);
  int wci  = (d & 7) * NB;
  float acc = 0.f;
#pragma unroll
  for (int b = 0; b < NB; ++b)
    acc += Wc[wci + b] * W[(b * DD + wrow) * OO + o];
  Vt[so * DD + d] = f2bf(acc);
}

// ---- H_s = X @ M_s  (bf16 MFMA, fp32 accum; validated R1-R6) ----
__global__ __launch_bounds__(256) void gemm_kernel(const uint16_t* __restrict__ X16,
                                                   const uint16_t* __restrict__ VtS,
                                                   uint16_t* __restrict__ H16){
  const int wave = threadIdx.x >> 6;
  const int lane = threadIdx.x & 63;
  const int lr = lane & 15, lk = lane >> 4;
  const int row0 = blockIdx.x * 64 + wave * 16;
  f32x4 acc[8];
#pragma unroll
  for (int t = 0; t < 8; ++t) acc[t] = (f32x4){0.f, 0.f, 0.f, 0.f};
  int arow = row0 + lr; if (arow >= NN) arow = NN - 1;
  const uint16_t* aptr = X16 + (size_t)arow * DD + lk * 8;
#pragma unroll
  for (int kb = 0; kb < DD; kb += 32){
    short8 a = *(const short8*)(aptr + kb);
#pragma unroll
    for (int t = 0; t < 8; ++t){
      short8 b = *(const short8*)(VtS + (size_t)(t * 16 + lr) * DD + kb + lk * 8);
      acc[t] = __builtin_amdgcn_mfma_f32_16x16x32_bf16(a, b, acc[t], 0, 0, 0);
    }
  }
#pragma unroll
  for (int t = 0; t < 8; ++t){
#pragma unroll
    for (int j = 0; j < 4; ++j){
      int r = row0 + lk * 4 + j;
      if (r < NN) H16[(size_t)r * OO + t * 16 + lr] = f2bf(acc[t][j]);
    }
  }
}

__device__ __noinline__ void overflow_add(int r, int c, float v,
                                          const uint16_t* __restrict__ H16,
                                          float* __restrict__ out){
  const uint16_t* h = H16 + (size_t)c * OO;
  float* dst = out + (size_t)r * OO;
  for (int d = 0; d < OO; ++d) unsafeAtomicAdd(dst + d, v * bf2f(h[d]));
}

// ---- bin: multisplit edges into 782 row-buckets via LDS staging; uint2 (8B) stores only ----
__global__ __launch_bounds__(1024) void bin_kernel(const int* __restrict__ rows,
                                                   const int* __restrict__ cols,
                                                   const float* __restrict__ vals,
                                                   const uint16_t* __restrict__ H16,
                                                   int* __restrict__ cursor,
                                                   uint2* __restrict__ gbuf,
                                                   float* __restrict__ out,
                                                   int E, int chunk, int rounds){
  __shared__ uint2 stage[NBUCK][SDEPTH];   // 50,048 B
  __shared__ int   scnt[NBUCK];            //  3,128 B
  const int tid = threadIdx.x;
  for (int i = tid; i < NBUCK; i += 1024) scnt[i] = 0;
  __syncthreads();
  const int e0 = blockIdx.x * chunk;
  for (int rd = 0; rd < rounds; ++rd){
    int idx = rd * 1024 + tid;
    int e = e0 + idx;
    if (idx < chunk && e < E){
      int r = rows[e], c = cols[e];
      float v = vals[e];
      int b = r >> 7;
      uint2 ent = make_uint2((uint32_t)(r & 127) | ((uint32_t)c << 7), __float_as_uint(v));
      int sp = atomicAdd(&scnt[b], 1);
      if (sp < SDEPTH){
        stage[b][sp] = ent;
      } else {                                   // rare in-round spill: direct to gbuf
        int pos = atomicAdd(&cursor[b * CPAD], 1);
        if (pos < BCAP) gbuf[(size_t)b * BCAP + pos] = ent;
        else overflow_add(r, c, v, H16, out);
      }
    }
    __syncthreads();
    if (tid < NBUCK){
      int b = tid;
      if (scnt[b] >= SDEPTH){
        int pos = atomicAdd(&cursor[b * CPAD], SDEPTH);
#pragma unroll
        for (int i = 0; i < SDEPTH; ++i){
          uint2 ent = stage[b][i];
          if (pos + i < BCAP) gbuf[(size_t)b * BCAP + pos + i] = ent;
          else overflow_add((b << 7) | (int)(ent.x & 127u), (int)(ent.x >> 7),
                            __uint_as_float(ent.y), H16, out);
        }
        scnt[b] = 0;
      }
    }
    __syncthreads();
  }
  // final drain of remainders (< SDEPTH each)
  if (tid < NBUCK){
    int b = tid;
    int n = scnt[b]; if (n > SDEPTH) n = SDEPTH;
    if (n > 0){
      int pos = atomicAdd(&cursor[b * CPAD], n);
      for (int i = 0; i < n; ++i){
        uint2 ent = stage[b][i];
        if (pos + i < BCAP) gbuf[(size_t)b * BCAP + pos + i] = ent;
        else overflow_add((b << 7) | (int)(ent.x & 127u), (int)(ent.x >> 7),
                          __uint_as_float(ent.y), H16, out);
      }
    }
  }
}

// ---- accum: one block per bucket; 64KB LDS f32 tile; lane L -> cols {L, L+64} (2-way banks) ----
template<bool LAST>
__global__ __launch_bounds__(1024) void accum_kernel(const uint2* __restrict__ gbuf,
                                                     int* __restrict__ cursor,
                                                     const uint16_t* __restrict__ H16,
                                                     float* __restrict__ out){
  __shared__ float tile[BROWS * OO];              // 65,536 B
  const int b = blockIdx.x;
  const int row0 = b * BROWS;
  const int nrows = (NN - row0 < BROWS) ? (NN - row0) : BROWS;
  const int tid = threadIdx.x;
  const int nel = nrows * OO;
  for (int i = tid; i < nel; i += 1024) tile[i] = out[(size_t)row0 * OO + i];
  __syncthreads();

  int entries = cursor[b * CPAD]; if (entries > BCAP) entries = BCAP;
  if (tid == 0) cursor[b * CPAD] = 0;             // fused re-zero for next pass
  const int wave = tid >> 6, lane = tid & 63;
  const uint2* bbase = gbuf + (size_t)b * BCAP;

  int i0 = wave * 4;
  for (; i0 + 4 <= entries; i0 += 64){
    uint2 p0 = bbase[i0], p1 = bbase[i0 + 1], p2 = bbase[i0 + 2], p3 = bbase[i0 + 3];
#pragma unroll
    for (int j = 0; j < 4; ++j){
      uint2 p = (j == 0) ? p0 : (j == 1) ? p1 : (j == 2) ? p2 : p3;
      int rl = (int)(p.x & 127u), c = (int)(p.x >> 7);
      float v = __uint_as_float(p.y);
      const uint16_t* h = H16 + (size_t)c * OO;
      float lo = bf2f(h[lane]), hi = bf2f(h[lane + 64]);
      atomicAdd(&tile[rl * OO + lane],      v * lo);
      atomicAdd(&tile[rl * OO + lane + 64], v * hi);
    }
  }
  for (int i = i0; i < entries && i < i0 + 4; ++i){
    uint2 p = bbase[i];
    int rl = (int)(p.x & 127u), c = (int)(p.x >> 7);
    float v = __uint_as_float(p.y);
    const uint16_t* h = H16 + (size_t)c * OO;
    atomicAdd(&tile[rl * OO + lane],      v * bf2f(h[lane]));
    atomicAdd(&tile[rl * OO + lane + 64], v * bf2f(h[lane + 64]));
  }
  __syncthreads();
  for (int i = tid; i < nel; i += 1024){
    float x = tile[i];
    if (LAST) x = fmaxf(x, 0.f);
    out[(size_t)row0 * OO + i] = x;
  }
}

// ---- fallback atomic spmm (R0-validated, only if ws too small) ----
__global__ __launch_bounds__(256) void spmm_kernel(const int* __restrict__ rows,
                                                   const int* __restrict__ cols,
                                                   const float* __restrict__ vals,
                                                   const uint16_t* __restrict__ H16,
                                                   float* __restrict__ out, int E){
  const int lane = threadIdx.x & 63;
  const int gwave = (int)((blockIdx.x * blockDim.x + threadIdx.x) >> 6);
  const int nw = (gridDim.x * blockDim.x) >> 6;
  for (int base = gwave * 64; base < E; base += nw * 64){
    int cnt = E - base; if (cnt > 64) cnt = 64;
    int r = 0, c = 0; float v = 0.f;
    if (lane < cnt){
      r = rows[base + lane]; c = cols[base + lane]; v = vals[base + lane];
    }
    for (int k = 0; k < cnt; ++k){
      int rr = __shfl(r, k);
      int cc = __shfl(c, k);
      float vv = __shfl(v, k);
      uint32_t pair = *(const uint32_t*)(H16 + (size_t)cc * OO + lane * 2);
      float* dst = out + (size_t)rr * OO + lane * 2;
      unsafeAtomicAdd(dst,     vv * bf2f((uint16_t)(pair & 0xFFFFu)));
      unsafeAtomicAdd(dst + 1, vv * bf2f((uint16_t)(pair >> 16)));
    }
  }
}

__global__ void relu_kernel(float* __restrict__ out, int n4){
  int i = blockIdx.x * blockDim.x + threadIdx.x;
  if (i < n4){
    float4 v = ((float4*)out)[i];
    v.x = fmaxf(v.x, 0.f); v.y = fmaxf(v.y, 0.f);
    v.z = fmaxf(v.z, 0.f); v.w = fmaxf(v.w, 0.f);
    ((float4*)out)[i] = v;
  }
}

extern "C" void kernel_launch(void* const* d_in, const int* in_sizes, int n_in,
                              void* d_out, int out_size, void* d_ws, size_t ws_size,
                              hipStream_t stream){
  const float* features = (const float*)d_in[0];
  const int*   rows     = (const int*)d_in[1];
  const int*   cols     = (const int*)d_in[2];
  const float* vals     = (const float*)d_in[3];
  const float* W        = (const float*)d_in[4];
  const float* Wc       = (const float*)d_in[5];
  float* out = (float*)d_out;
  const int E = in_sizes[1] / NS;

  char* ws = (char*)d_ws;
  uint16_t* X16    = (uint16_t*)ws;                     // 25,600,000
  uint16_t* Vt     = (uint16_t*)(ws + 25600000);        //    262,144
  uint16_t* H16    = (uint16_t*)(ws + 25862144);        // 25,600,000
  int*      cursor = (int*)     (ws + 51462144);        //     50,048 (782 x 64B padded)
  uint2*    gbuf   = (uint2*)   (ws + 51512192);        // 15,214,592 (782 x 2432 x 8B)
  const size_t NEEDED = 51512192 + (size_t)NBUCK * BCAP * 8;   // 66,726,784 < known-good ws (>= 90,262,144)

  hipMemsetAsync(d_out, 0, (size_t)out_size * sizeof(float), stream);
  cast_bf16_kernel<<<(NN * DD / 4 + 255) / 256, 256, 0, stream>>>(features, X16, NN * DD / 4);
  vt_kernel<<<NS * OO, DD, 0, stream>>>(W, Wc, Vt);

  if (ws_size >= NEEDED){
    hipMemsetAsync(cursor, 0, (size_t)NBUCK * CPAD * sizeof(int), stream);  // once; accum re-zeroes
    const int chunk  = (E + 255) / 256;
    const int rounds = (chunk + 1023) / 1024;
    for (int s = 0; s < NS; ++s){
      gemm_kernel<<<(NN + 63) / 64, 256, 0, stream>>>(X16, Vt + (size_t)s * DD * OO, H16);
      bin_kernel<<<256, 1024, 0, stream>>>(rows + (size_t)s * E, cols + (size_t)s * E,
                                           vals + (size_t)s * E, H16, cursor, gbuf, out,
                                           E, chunk, rounds);
      if (s == NS - 1)
        accum_kernel<true><<<NBUCK, 1024, 0, stream>>>(gbuf, cursor, H16, out);
      else
        accum_kernel<false><<<NBUCK, 1024, 0, stream>>>(gbuf, cursor, H16, out);
    }
  } else {
    for (int s = 0; s < NS; ++s){
      gemm_kernel<<<(NN + 63) / 64, 256, 0, stream>>>(X16, Vt + (size_t)s * DD * OO, H16);
      spmm_kernel<<<4096, 256, 0, stream>>>(rows + (size_t)s * E, cols + (size_t)s * E,
                                            vals + (size_t)s * E, H16, out, E);
    }
    relu_kernel<<<(NN * OO / 4 + 255) / 256, 256, 0, stream>>>(out, NN * OO / 4);
  }
}

// Round 9
// 1212.973 us; speedup vs baseline: 9.2375x; 9.2375x over previous
//
#include <hip/hip_runtime.h>
#include <hip/hip_bf16.h>
#include <stdint.h>

#define NN 100000   // nodes
#define DD 128      // input dim
#define OO 128      // output dim
#define NS 8        // relations
#define NB 4        // bases

#define BROWS 128   // rows per bucket
#define NBUCK 782   // ceil(NN/BROWS)
#define SDEPTH 8    // bin LDS staging depth per bucket
#define BCAP 2432   // per-bucket capacity (mean 2046 + ~8.5 sigma; overflow handled)
#define CPAD 16     // cursor padding (ints) = 64B per counter

typedef __attribute__((ext_vector_type(8))) short short8;
typedef __attribute__((ext_vector_type(4))) float f32x4;

__device__ __forceinline__ float bf2f(uint16_t u){
  union { uint32_t i; float f; } x; x.i = ((uint32_t)u) << 16; return x.f;
}
__device__ __forceinline__ uint16_t f2bf(float f){
  union { float f; uint32_t i; } x; x.f = f;
  uint32_t r = (x.i + 0x7FFFu + ((x.i >> 16) & 1u)) >> 16;  // RNE
  return (uint16_t)r;
}

// ---- cast features f32 -> bf16 ----
__global__ void cast_bf16_kernel(const float* __restrict__ in, uint16_t* __restrict__ out, int n4){
  int i = blockIdx.x * blockDim.x + threadIdx.x;
  if (i < n4){
    float4 v = ((const float4*)in)[i];
    ushort4 o;
    o.x = f2bf(v.x); o.y = f2bf(v.y); o.z = f2bf(v.z); o.w = f2bf(v.w);
    ((ushort4*)out)[i] = o;
  }
}

// ---- effective per-relation weight, TRANSPOSED: Vt[s][o][d] = M_s[d][o] ----
// M_s[d,o] = sum_b W_comp[d&7, b] * W[b*128 + s*16 + (d>>3), o]  (validated R1-R8)
__global__ void vt_kernel(const float* __restrict__ W, const float* __restrict__ Wc,
                          uint16_t* __restrict__ Vt){
  int d  = threadIdx.x;
  int so = blockIdx.x;
  int s = so >> 7, o = so & 127;
  int wrow = s * 16 + (d >> 3);
  int wci  = (d & 7) * NB;
  float acc = 0.f;
#pragma unroll
  for (int b = 0; b < NB; ++b)
    acc += Wc[wci + b] * W[(b * DD + wrow) * OO + o];
  Vt[so * DD + d] = f2bf(acc);
}

// ---- H_s = X @ M_s  (bf16 MFMA, fp32 accum; validated R1-R8) ----
__global__ __launch_bounds__(256) void gemm_kernel(const uint16_t* __restrict__ X16,
                                                   const uint16_t* __restrict__ VtS,
                                                   uint16_t* __restrict__ H16){
  const int wave = threadIdx.x >> 6;
  const int lane = threadIdx.x & 63;
  const int lr = lane & 15, lk = lane >> 4;
  const int row0 = blockIdx.x * 64 + wave * 16;
  f32x4 acc[8];
#pragma unroll
  for (int t = 0; t < 8; ++t) acc[t] = (f32x4){0.f, 0.f, 0.f, 0.f};
  int arow = row0 + lr; if (arow >= NN) arow = NN - 1;
  const uint16_t* aptr = X16 + (size_t)arow * DD + lk * 8;
#pragma unroll
  for (int kb = 0; kb < DD; kb += 32){
    short8 a = *(const short8*)(aptr + kb);
#pragma unroll
    for (int t = 0; t < 8; ++t){
      short8 b = *(const short8*)(VtS + (size_t)(t * 16 + lr) * DD + kb + lk * 8);
      acc[t] = __builtin_amdgcn_mfma_f32_16x16x32_bf16(a, b, acc[t], 0, 0, 0);
    }
  }
#pragma unroll
  for (int t = 0; t < 8; ++t){
#pragma unroll
    for (int j = 0; j < 4; ++j){
      int r = row0 + lk * 4 + j;
      if (r < NN) H16[(size_t)r * OO + t * 16 + lr] = f2bf(acc[t][j]);
    }
  }
}

__device__ __noinline__ void overflow_add(int r, int c, float v,
                                          const uint16_t* __restrict__ H16,
                                          float* __restrict__ out){
  const uint16_t* h = H16 + (size_t)c * OO;
  float* dst = out + (size_t)r * OO;
  for (int d = 0; d < OO; ++d) unsafeAtomicAdd(dst + d, v * bf2f(h[d]));
}

// ---- bin: multisplit edges into 782 row-buckets via LDS staging (R8-validated) ----
__global__ __launch_bounds__(1024) void bin_kernel(const int* __restrict__ rows,
                                                   const int* __restrict__ cols,
                                                   const float* __restrict__ vals,
                                                   const uint16_t* __restrict__ H16,
                                                   int* __restrict__ cursor,
                                                   uint2* __restrict__ gbuf,
                                                   float* __restrict__ out,
                                                   int E, int chunk, int rounds){
  __shared__ uint2 stage[NBUCK][SDEPTH];   // 50,048 B
  __shared__ int   scnt[NBUCK];            //  3,128 B
  const int tid = threadIdx.x;
  for (int i = tid; i < NBUCK; i += 1024) scnt[i] = 0;
  __syncthreads();
  const int e0 = blockIdx.x * chunk;
  for (int rd = 0; rd < rounds; ++rd){
    int idx = rd * 1024 + tid;
    int e = e0 + idx;
    if (idx < chunk && e < E){
      int r = rows[e], c = cols[e];
      float v = vals[e];
      int b = r >> 7;
      uint2 ent = make_uint2((uint32_t)(r & 127) | ((uint32_t)c << 7), __float_as_uint(v));
      int sp = atomicAdd(&scnt[b], 1);
      if (sp < SDEPTH){
        stage[b][sp] = ent;
      } else {
        int pos = atomicAdd(&cursor[b * CPAD], 1);
        if (pos < BCAP) gbuf[(size_t)b * BCAP + pos] = ent;
        else overflow_add(r, c, v, H16, out);
      }
    }
    __syncthreads();
    if (tid < NBUCK){
      int b = tid;
      if (scnt[b] >= SDEPTH){
        int pos = atomicAdd(&cursor[b * CPAD], SDEPTH);
#pragma unroll
        for (int i = 0; i < SDEPTH; ++i){
          uint2 ent = stage[b][i];
          if (pos + i < BCAP) gbuf[(size_t)b * BCAP + pos + i] = ent;
          else overflow_add((b << 7) | (int)(ent.x & 127u), (int)(ent.x >> 7),
                            __uint_as_float(ent.y), H16, out);
        }
        scnt[b] = 0;
      }
    }
    __syncthreads();
  }
  if (tid < NBUCK){
    int b = tid;
    int n = scnt[b]; if (n > SDEPTH) n = SDEPTH;
    if (n > 0){
      int pos = atomicAdd(&cursor[b * CPAD], n);
      for (int i = 0; i < n; ++i){
        uint2 ent = stage[b][i];
        if (pos + i < BCAP) gbuf[(size_t)b * BCAP + pos + i] = ent;
        else overflow_add((b << 7) | (int)(ent.x & 127u), (int)(ent.x >> 7),
                          __uint_as_float(ent.y), H16, out);
      }
    }
  }
}

// ---- accum2: LDS row-sort, then register-accumulating gather (NO float atomics) ----
template<bool LAST>
__global__ __launch_bounds__(1024) void accum2_kernel(const uint2* __restrict__ gbuf,
                                                      int* __restrict__ cursor,
                                                      const uint16_t* __restrict__ H16,
                                                      float* __restrict__ out){
  __shared__ uint2 raw[BCAP];     // 19,456 B
  __shared__ uint2 srt[BCAP];     // 19,456 B
  __shared__ int   cnt[BROWS];    //    512 B
  __shared__ int   pos[BROWS];    //    512 B  (row start offsets)
  __shared__ int   cur[BROWS];    //    512 B  (reorder cursors)
  __shared__ int   entS;
  const int b = blockIdx.x;
  const int row0 = b * BROWS;
  const int tid = threadIdx.x;

  if (tid == 0){
    int e = cursor[b * CPAD]; if (e > BCAP) e = BCAP;
    entS = e;
  }
  if (tid < BROWS) cnt[tid] = 0;
  __syncthreads();
  const int entries = entS;
  if (tid == 0) cursor[b * CPAD] = 0;          // re-zero for next pass (entS already latched)

  // load entries + row histogram (native int LDS atomics)
  for (int i = tid; i < entries; i += 1024){
    uint2 e = gbuf[(size_t)b * BCAP + i];
    raw[i] = e;
    atomicAdd(&cnt[e.x & 127u], 1);
  }
  __syncthreads();

  // exclusive prefix over 128 counts: wave 0, 2 counts per lane, shfl scan
  if (tid < 64){
    int a  = cnt[2 * tid];
    int c2 = cnt[2 * tid + 1];
    int s  = a + c2;
#pragma unroll
    for (int d = 1; d < 64; d <<= 1){
      int t = __shfl_up(s, d);
      if (tid >= d) s += t;
    }
    int excl = s - (a + c2);
    pos[2 * tid]     = excl;
    pos[2 * tid + 1] = excl + a;
    cur[2 * tid]     = excl;
    cur[2 * tid + 1] = excl + a;
  }
  __syncthreads();

  // reorder into row-sorted LDS
  for (int i = tid; i < entries; i += 1024){
    uint2 e = raw[i];
    int p = atomicAdd(&cur[e.x & 127u], 1);
    srt[p] = e;
  }
  __syncthreads();

  // process: wave w handles 8 rows; register float2 accumulation; one RMW of out per row
  const int wave = tid >> 6, lane = tid & 63;
#pragma unroll
  for (int rr = 0; rr < 8; ++rr){
    int rl = wave * 8 + rr;
    int row = row0 + rl;
    if (row >= NN) break;
    int n  = cnt[rl];
    int b0 = pos[rl];
    float2 acc = *(const float2*)(out + (size_t)row * OO + lane * 2);
    int k = 0;
    for (; k + 4 <= n; k += 4){
      uint2 e0 = srt[b0 + k],     e1 = srt[b0 + k + 1];
      uint2 e2 = srt[b0 + k + 2], e3 = srt[b0 + k + 3];
      uint32_t q0 = ((const uint32_t*)(H16 + (size_t)(e0.x >> 7) * OO))[lane];
      uint32_t q1 = ((const uint32_t*)(H16 + (size_t)(e1.x >> 7) * OO))[lane];
      uint32_t q2 = ((const uint32_t*)(H16 + (size_t)(e2.x >> 7) * OO))[lane];
      uint32_t q3 = ((const uint32_t*)(H16 + (size_t)(e3.x >> 7) * OO))[lane];
      float v0 = __uint_as_float(e0.y), v1 = __uint_as_float(e1.y);
      float v2 = __uint_as_float(e2.y), v3 = __uint_as_float(e3.y);
      acc.x += v0 * bf2f((uint16_t)(q0 & 0xFFFFu));  acc.y += v0 * bf2f((uint16_t)(q0 >> 16));
      acc.x += v1 * bf2f((uint16_t)(q1 & 0xFFFFu));  acc.y += v1 * bf2f((uint16_t)(q1 >> 16));
      acc.x += v2 * bf2f((uint16_t)(q2 & 0xFFFFu));  acc.y += v2 * bf2f((uint16_t)(q2 >> 16));
      acc.x += v3 * bf2f((uint16_t)(q3 & 0xFFFFu));  acc.y += v3 * bf2f((uint16_t)(q3 >> 16));
    }
    for (; k < n; ++k){
      uint2 e = srt[b0 + k];
      uint32_t q = ((const uint32_t*)(H16 + (size_t)(e.x >> 7) * OO))[lane];
      float v = __uint_as_float(e.y);
      acc.x += v * bf2f((uint16_t)(q & 0xFFFFu));
      acc.y += v * bf2f((uint16_t)(q >> 16));
    }
    if (LAST){ acc.x = fmaxf(acc.x, 0.f); acc.y = fmaxf(acc.y, 0.f); }
    *(float2*)(out + (size_t)row * OO + lane * 2) = acc;
  }
}

// ---- fallback atomic spmm (R0-validated, only if ws too small) ----
__global__ __launch_bounds__(256) void spmm_kernel(const int* __restrict__ rows,
                                                   const int* __restrict__ cols,
                                                   const float* __restrict__ vals,
                                                   const uint16_t* __restrict__ H16,
                                                   float* __restrict__ out, int E){
  const int lane = threadIdx.x & 63;
  const int gwave = (int)((blockIdx.x * blockDim.x + threadIdx.x) >> 6);
  const int nw = (gridDim.x * blockDim.x) >> 6;
  for (int base = gwave * 64; base < E; base += nw * 64){
    int cnt = E - base; if (cnt > 64) cnt = 64;
    int r = 0, c = 0; float v = 0.f;
    if (lane < cnt){
      r = rows[base + lane]; c = cols[base + lane]; v = vals[base + lane];
    }
    for (int k = 0; k < cnt; ++k){
      int rr = __shfl(r, k);
      int cc = __shfl(c, k);
      float vv = __shfl(v, k);
      uint32_t pair = *(const uint32_t*)(H16 + (size_t)cc * OO + lane * 2);
      float* dst = out + (size_t)rr * OO + lane * 2;
      unsafeAtomicAdd(dst,     vv * bf2f((uint16_t)(pair & 0xFFFFu)));
      unsafeAtomicAdd(dst + 1, vv * bf2f((uint16_t)(pair >> 16)));
    }
  }
}

__global__ void relu_kernel(float* __restrict__ out, int n4){
  int i = blockIdx.x * blockDim.x + threadIdx.x;
  if (i < n4){
    float4 v = ((float4*)out)[i];
    v.x = fmaxf(v.x, 0.f); v.y = fmaxf(v.y, 0.f);
    v.z = fmaxf(v.z, 0.f); v.w = fmaxf(v.w, 0.f);
    ((float4*)out)[i] = v;
  }
}

extern "C" void kernel_launch(void* const* d_in, const int* in_sizes, int n_in,
                              void* d_out, int out_size, void* d_ws, size_t ws_size,
                              hipStream_t stream){
  const float* features = (const float*)d_in[0];
  const int*   rows     = (const int*)d_in[1];
  const int*   cols     = (const int*)d_in[2];
  const float* vals     = (const float*)d_in[3];
  const float* W        = (const float*)d_in[4];
  const float* Wc       = (const float*)d_in[5];
  float* out = (float*)d_out;
  const int E = in_sizes[1] / NS;

  char* ws = (char*)d_ws;
  uint16_t* X16    = (uint16_t*)ws;                     // 25,600,000
  uint16_t* Vt     = (uint16_t*)(ws + 25600000);        //    262,144
  uint16_t* H16    = (uint16_t*)(ws + 25862144);        // 25,600,000
  int*      cursor = (int*)     (ws + 51462144);        //     50,048 (782 x 64B padded)
  uint2*    gbuf   = (uint2*)   (ws + 51512192);        // 15,214,592 (782 x 2432 x 8B)
  const size_t NEEDED = 51512192 + (size_t)NBUCK * BCAP * 8;   // 66,726,784 < known-good ws (>= 90,262,144)

  hipMemsetAsync(d_out, 0, (size_t)out_size * sizeof(float), stream);
  cast_bf16_kernel<<<(NN * DD / 4 + 255) / 256, 256, 0, stream>>>(features, X16, NN * DD / 4);
  vt_kernel<<<NS * OO, DD, 0, stream>>>(W, Wc, Vt);

  if (ws_size >= NEEDED){
    hipMemsetAsync(cursor, 0, (size_t)NBUCK * CPAD * sizeof(int), stream);  // once; accum2 re-zeroes
    const int chunk  = (E + 255) / 256;
    const int rounds = (chunk + 1023) / 1024;
    for (int s = 0; s < NS; ++s){
      gemm_kernel<<<(NN + 63) / 64, 256, 0, stream>>>(X16, Vt + (size_t)s * DD * OO, H16);
      bin_kernel<<<256, 1024, 0, stream>>>(rows + (size_t)s * E, cols + (size_t)s * E,
                                           vals + (size_t)s * E, H16, cursor, gbuf, out,
                                           E, chunk, rounds);
      if (s == NS - 1)
        accum2_kernel<true><<<NBUCK, 1024, 0, stream>>>(gbuf, cursor, H16, out);
      else
        accum2_kernel<false><<<NBUCK, 1024, 0, stream>>>(gbuf, cursor, H16, out);
    }
  } else {
    for (int s = 0; s < NS; ++s){
      gemm_kernel<<<(NN + 63) / 64, 256, 0, stream>>>(X16, Vt + (size_t)s * DD * OO, H16);
      spmm_kernel<<<4096, 256, 0, stream>>>(rows + (size_t)s * E, cols + (size_t)s * E,
                                            vals + (size_t)s * E, H16, out, E);
    }
    relu_kernel<<<(NN * OO / 4 + 255) / 256, 256, 0, stream>>>(out, NN * OO / 4);
  }
}

// Round 10
// 1034.088 us; speedup vs baseline: 10.8354x; 1.1730x over previous
//
#include <hip/hip_runtime.h>
#include <hip/hip_bf16.h>
#include <stdint.h>

#define NN 100000   // nodes
#define DD 128      // input dim
#define OO 128      // output dim
#define NS 8        // relations
#define NB 4        // bases

#define BROWS 128   // rows per bucket
#define NBUCK 782   // ceil(NN/BROWS)
#define SDEPTH 8    // bin LDS staging depth per bucket
#define BCAP 4608   // per-bucket capacity for a 2-relation group (mean 4092 + 8 sigma)
#define CPAD 16     // cursor padding (ints) = 64B per counter

typedef __attribute__((ext_vector_type(8))) short short8;
typedef __attribute__((ext_vector_type(4))) float f32x4;

__device__ __forceinline__ float bf2f(uint16_t u){
  union { uint32_t i; float f; } x; x.i = ((uint32_t)u) << 16; return x.f;
}
__device__ __forceinline__ uint16_t f2bf(float f){
  union { float f; uint32_t i; } x; x.f = f;
  uint32_t r = (x.i + 0x7FFFu + ((x.i >> 16) & 1u)) >> 16;  // RNE
  return (uint16_t)r;
}

// ---- effective per-relation weight, TRANSPOSED: Vt[s][o][d] = M_s[d][o] ----
// M_s[d,o] = sum_b W_comp[d&7, b] * W[b*128 + s*16 + (d>>3), o]  (validated R1-R9)
__global__ void vt_kernel(const float* __restrict__ W, const float* __restrict__ Wc,
                          uint16_t* __restrict__ Vt){
  int d  = threadIdx.x;
  int so = blockIdx.x;
  int s = so >> 7, o = so & 127;
  int wrow = s * 16 + (d >> 3);
  int wci  = (d & 7) * NB;
  float acc = 0.f;
#pragma unroll
  for (int b = 0; b < NB; ++b)
    acc += Wc[wci + b] * W[(b * DD + wrow) * OO + o];
  Vt[so * DD + d] = f2bf(acc);
}

// ---- gemm2: H_{s0}, H_{s0+1} = X @ M; reads f32 X once, casts in-register ----
// body is the R1-R9-validated gemm with the A-fragment cast folded in and a 2-iter s-loop
__global__ __launch_bounds__(256) void gemm2_kernel(const float* __restrict__ X,
                                                    const uint16_t* __restrict__ Vt2,
                                                    uint16_t* __restrict__ H2){
  const int wave = threadIdx.x >> 6;
  const int lane = threadIdx.x & 63;
  const int lr = lane & 15, lk = lane >> 4;
  const int row0 = blockIdx.x * 64 + wave * 16;

  int arow = row0 + lr; if (arow >= NN) arow = NN - 1;   // clamp (stores guarded)
  const float* ap = X + (size_t)arow * DD;
  short8 a[4];
#pragma unroll
  for (int kb = 0; kb < 4; ++kb){
    float4 f0 = *(const float4*)(ap + kb * 32 + lk * 8);
    float4 f1 = *(const float4*)(ap + kb * 32 + lk * 8 + 4);
    short8 t;
    t[0] = (short)f2bf(f0.x); t[1] = (short)f2bf(f0.y);
    t[2] = (short)f2bf(f0.z); t[3] = (short)f2bf(f0.w);
    t[4] = (short)f2bf(f1.x); t[5] = (short)f2bf(f1.y);
    t[6] = (short)f2bf(f1.z); t[7] = (short)f2bf(f1.w);
    a[kb] = t;
  }

  for (int j = 0; j < 2; ++j){
    f32x4 acc[8];
#pragma unroll
    for (int t = 0; t < 8; ++t) acc[t] = (f32x4){0.f, 0.f, 0.f, 0.f};
    const uint16_t* vb = Vt2 + (size_t)j * OO * DD;
#pragma unroll
    for (int kb = 0; kb < 4; ++kb){
#pragma unroll
      for (int t = 0; t < 8; ++t){
        short8 b = *(const short8*)(vb + (size_t)(t * 16 + lr) * DD + kb * 32 + lk * 8);
        acc[t] = __builtin_amdgcn_mfma_f32_16x16x32_bf16(a[kb], b, acc[t], 0, 0, 0);
      }
    }
    uint16_t* hs = H2 + (size_t)j * NN * OO;
    // C/D layout: col = lane&15, row = (lane>>4)*4 + reg   [learn_hip m89]
#pragma unroll
    for (int t = 0; t < 8; ++t){
#pragma unroll
      for (int jj = 0; jj < 4; ++jj){
        int r = row0 + lk * 4 + jj;
        if (r < NN) hs[(size_t)r * OO + t * 16 + lr] = f2bf(acc[t][jj]);
      }
    }
  }
}

// overflow entry decode: rl[0:6], col[7:23], s[24]
__device__ __noinline__ void overflow_add(int r, int c, int srel, float v,
                                          const uint16_t* __restrict__ H2,
                                          float* __restrict__ out){
  const uint16_t* h = H2 + (size_t)srel * NN * OO + (size_t)c * OO;
  float* dst = out + (size_t)r * OO;
  for (int d = 0; d < OO; ++d) unsafeAtomicAdd(dst + d, v * bf2f(h[d]));
}

// ---- bin2: multisplit 2 relations' edges (contiguous 2E range) into row-buckets ----
__global__ __launch_bounds__(1024) void bin2_kernel(const int* __restrict__ rows2,
                                                    const int* __restrict__ cols2,
                                                    const float* __restrict__ vals2,
                                                    const uint16_t* __restrict__ H2,
                                                    int* __restrict__ cursor,
                                                    uint2* __restrict__ gbuf,
                                                    float* __restrict__ out,
                                                    int E, int chunk, int rounds){
  __shared__ uint2 stage[NBUCK][SDEPTH];   // 50,048 B
  __shared__ int   scnt[NBUCK];            //  3,128 B
  const int tid = threadIdx.x;
  const int E2 = 2 * E;
  for (int i = tid; i < NBUCK; i += 1024) scnt[i] = 0;
  __syncthreads();
  const int e0 = blockIdx.x * chunk;
  for (int rd = 0; rd < rounds; ++rd){
    int idx = rd * 1024 + tid;
    int e = e0 + idx;
    if (idx < chunk && e < E2){
      int r = rows2[e], c = cols2[e];
      float v = vals2[e];
      uint32_t srel = (e >= E) ? 1u : 0u;
      int b = r >> 7;
      uint2 ent = make_uint2((uint32_t)(r & 127) | ((uint32_t)c << 7) | (srel << 24),
                             __float_as_uint(v));
      int sp = atomicAdd(&scnt[b], 1);
      if (sp < SDEPTH){
        stage[b][sp] = ent;
      } else {
        int pos = atomicAdd(&cursor[b * CPAD], 1);
        if (pos < BCAP) gbuf[(size_t)b * BCAP + pos] = ent;
        else overflow_add(r, c, (int)srel, v, H2, out);
      }
    }
    __syncthreads();
    if (tid < NBUCK){
      int b = tid;
      if (scnt[b] >= SDEPTH){
        int pos = atomicAdd(&cursor[b * CPAD], SDEPTH);
#pragma unroll
        for (int i = 0; i < SDEPTH; ++i){
          uint2 ent = stage[b][i];
          if (pos + i < BCAP) gbuf[(size_t)b * BCAP + pos + i] = ent;
          else overflow_add((b << 7) | (int)(ent.x & 127u), (int)((ent.x >> 7) & 0x1FFFFu),
                            (int)(ent.x >> 24), __uint_as_float(ent.y), H2, out);
        }
        scnt[b] = 0;
      }
    }
    __syncthreads();
  }
  if (tid < NBUCK){
    int b = tid;
    int n = scnt[b]; if (n > SDEPTH) n = SDEPTH;
    if (n > 0){
      int pos = atomicAdd(&cursor[b * CPAD], n);
      for (int i = 0; i < n; ++i){
        uint2 ent = stage[b][i];
        if (pos + i < BCAP) gbuf[(size_t)b * BCAP + pos + i] = ent;
        else overflow_add((b << 7) | (int)(ent.x & 127u), (int)((ent.x >> 7) & 0x1FFFFu),
                          (int)(ent.x >> 24), __uint_as_float(ent.y), H2, out);
      }
    }
  }
}

// ---- accum2d: LDS row-sort (both relations merged per row) + register gather ----
template<bool LAST>
__global__ __launch_bounds__(1024) void accum2d_kernel(const uint2* __restrict__ gbuf,
                                                       int* __restrict__ cursor,
                                                       const uint16_t* __restrict__ H2,
                                                       float* __restrict__ out){
  __shared__ uint2 raw[BCAP];     // 36,864 B
  __shared__ uint2 srt[BCAP];     // 36,864 B
  __shared__ int   cnt[BROWS];
  __shared__ int   pos[BROWS];
  __shared__ int   cur[BROWS];
  __shared__ int   entS;
  const int b = blockIdx.x;
  const int row0 = b * BROWS;
  const int tid = threadIdx.x;

  if (tid == 0){
    int e = cursor[b * CPAD]; if (e > BCAP) e = BCAP;
    entS = e;
  }
  if (tid < BROWS) cnt[tid] = 0;
  __syncthreads();
  const int entries = entS;
  if (tid == 0) cursor[b * CPAD] = 0;          // re-zero for next group (entS latched)

  for (int i = tid; i < entries; i += 1024){
    uint2 e = gbuf[(size_t)b * BCAP + i];
    raw[i] = e;
    atomicAdd(&cnt[e.x & 127u], 1);
  }
  __syncthreads();

  if (tid < 64){
    int a  = cnt[2 * tid];
    int c2 = cnt[2 * tid + 1];
    int s  = a + c2;
#pragma unroll
    for (int d = 1; d < 64; d <<= 1){
      int t = __shfl_up(s, d);
      if (tid >= d) s += t;
    }
    int excl = s - (a + c2);
    pos[2 * tid]     = excl;
    pos[2 * tid + 1] = excl + a;
    cur[2 * tid]     = excl;
    cur[2 * tid + 1] = excl + a;
  }
  __syncthreads();

  for (int i = tid; i < entries; i += 1024){
    uint2 e = raw[i];
    int p = atomicAdd(&cur[e.x & 127u], 1);
    srt[p] = e;
  }
  __syncthreads();

  const int wave = tid >> 6, lane = tid & 63;
#pragma unroll
  for (int rr = 0; rr < 8; ++rr){
    int rl = wave * 8 + rr;
    int row = row0 + rl;
    if (row >= NN) break;
    int n  = cnt[rl];
    int b0 = pos[rl];
    float2 acc = *(const float2*)(out + (size_t)row * OO + lane * 2);
    int k = 0;
    for (; k + 8 <= n; k += 8){
      float accx = 0.f, accy = 0.f;
#pragma unroll
      for (int j = 0; j < 8; ++j){
        uint2 e = srt[b0 + k + j];
        const uint16_t* h = H2 + (size_t)(e.x >> 24) * (NN * OO)
                               + (size_t)((e.x >> 7) & 0x1FFFFu) * OO;
        uint32_t q = ((const uint32_t*)h)[lane];
        float v = __uint_as_float(e.y);
        accx += v * bf2f((uint16_t)(q & 0xFFFFu));
        accy += v * bf2f((uint16_t)(q >> 16));
      }
      acc.x += accx; acc.y += accy;
    }
    for (; k < n; ++k){
      uint2 e = srt[b0 + k];
      const uint16_t* h = H2 + (size_t)(e.x >> 24) * (NN * OO)
                             + (size_t)((e.x >> 7) & 0x1FFFFu) * OO;
      uint32_t q = ((const uint32_t*)h)[lane];
      float v = __uint_as_float(e.y);
      acc.x += v * bf2f((uint16_t)(q & 0xFFFFu));
      acc.y += v * bf2f((uint16_t)(q >> 16));
    }
    if (LAST){ acc.x = fmaxf(acc.x, 0.f); acc.y = fmaxf(acc.y, 0.f); }
    *(float2*)(out + (size_t)row * OO + lane * 2) = acc;
  }
}

// ======== fallback (R2/R6-validated path pieces, only if ws too small) ========
__global__ void cast_bf16_kernel(const float* __restrict__ in, uint16_t* __restrict__ out, int n4){
  int i = blockIdx.x * blockDim.x + threadIdx.x;
  if (i < n4){
    float4 v = ((const float4*)in)[i];
    ushort4 o;
    o.x = f2bf(v.x); o.y = f2bf(v.y); o.z = f2bf(v.z); o.w = f2bf(v.w);
    ((ushort4*)out)[i] = o;
  }
}

__global__ __launch_bounds__(256) void gemm_kernel(const uint16_t* __restrict__ X16,
                                                   const uint16_t* __restrict__ VtS,
                                                   uint16_t* __restrict__ H16){
  const int wave = threadIdx.x >> 6;
  const int lane = threadIdx.x & 63;
  const int lr = lane & 15, lk = lane >> 4;
  const int row0 = blockIdx.x * 64 + wave * 16;
  f32x4 acc[8];
#pragma unroll
  for (int t = 0; t < 8; ++t) acc[t] = (f32x4){0.f, 0.f, 0.f, 0.f};
  int arow = row0 + lr; if (arow >= NN) arow = NN - 1;
  const uint16_t* aptr = X16 + (size_t)arow * DD + lk * 8;
#pragma unroll
  for (int kb = 0; kb < DD; kb += 32){
    short8 a = *(const short8*)(aptr + kb);
#pragma unroll
    for (int t = 0; t < 8; ++t){
      short8 b = *(const short8*)(VtS + (size_t)(t * 16 + lr) * DD + kb + lk * 8);
      acc[t] = __builtin_amdgcn_mfma_f32_16x16x32_bf16(a, b, acc[t], 0, 0, 0);
    }
  }
#pragma unroll
  for (int t = 0; t < 8; ++t){
#pragma unroll
    for (int j = 0; j < 4; ++j){
      int r = row0 + lk * 4 + j;
      if (r < NN) H16[(size_t)r * OO + t * 16 + lr] = f2bf(acc[t][j]);
    }
  }
}

__global__ __launch_bounds__(256) void spmm_kernel(const int* __restrict__ rows,
                                                   const int* __restrict__ cols,
                                                   const float* __restrict__ vals,
                                                   const uint16_t* __restrict__ H16,
                                                   float* __restrict__ out, int E){
  const int lane = threadIdx.x & 63;
  const int gwave = (int)((blockIdx.x * blockDim.x + threadIdx.x) >> 6);
  const int nw = (gridDim.x * blockDim.x) >> 6;
  for (int base = gwave * 64; base < E; base += nw * 64){
    int cnt = E - base; if (cnt > 64) cnt = 64;
    int r = 0, c = 0; float v = 0.f;
    if (lane < cnt){
      r = rows[base + lane]; c = cols[base + lane]; v = vals[base + lane];
    }
    for (int k = 0; k < cnt; ++k){
      int rr = __shfl(r, k);
      int cc = __shfl(c, k);
      float vv = __shfl(v, k);
      uint32_t pair = *(const uint32_t*)(H16 + (size_t)cc * OO + lane * 2);
      float* dst = out + (size_t)rr * OO + lane * 2;
      unsafeAtomicAdd(dst,     vv * bf2f((uint16_t)(pair & 0xFFFFu)));
      unsafeAtomicAdd(dst + 1, vv * bf2f((uint16_t)(pair >> 16)));
    }
  }
}

__global__ void relu_kernel(float* __restrict__ out, int n4){
  int i = blockIdx.x * blockDim.x + threadIdx.x;
  if (i < n4){
    float4 v = ((float4*)out)[i];
    v.x = fmaxf(v.x, 0.f); v.y = fmaxf(v.y, 0.f);
    v.z = fmaxf(v.z, 0.f); v.w = fmaxf(v.w, 0.f);
    ((float4*)out)[i] = v;
  }
}
// =============================================================================

extern "C" void kernel_launch(void* const* d_in, const int* in_sizes, int n_in,
                              void* d_out, int out_size, void* d_ws, size_t ws_size,
                              hipStream_t stream){
  const float* features = (const float*)d_in[0];
  const int*   rows     = (const int*)d_in[1];
  const int*   cols     = (const int*)d_in[2];
  const float* vals     = (const float*)d_in[3];
  const float* W        = (const float*)d_in[4];
  const float* Wc       = (const float*)d_in[5];
  float* out = (float*)d_out;
  const int E = in_sizes[1] / NS;

  char* ws = (char*)d_ws;
  // ---- main layout ----
  uint16_t* Vt     = (uint16_t*)ws;                     //    262,144
  uint16_t* H2     = (uint16_t*)(ws + 262144);          // 51,200,000 (2 relations)
  int*      cursor = (int*)     (ws + 51462144);        //     50,048
  uint2*    gbuf   = (uint2*)   (ws + 51512192);        // 28,827,648 (782 x 4608 x 8B)
  const size_t NEEDED = 51512192 + (size_t)NBUCK * BCAP * 8;   // 80,339,840 < proven ws >= 90,262,144

  hipMemsetAsync(d_out, 0, (size_t)out_size * sizeof(float), stream);

  if (ws_size >= NEEDED){
    vt_kernel<<<NS * OO, DD, 0, stream>>>(W, Wc, Vt);
    hipMemsetAsync(cursor, 0, (size_t)NBUCK * CPAD * sizeof(int), stream);  // once; accum re-zeroes
    const int chunk  = (2 * E + 255) / 256;
    const int rounds = (chunk + 1023) / 1024;
    for (int g = 0; g < 4; ++g){
      gemm2_kernel<<<(NN + 63) / 64, 256, 0, stream>>>(
          features, Vt + (size_t)(2 * g) * OO * DD, H2);
      bin2_kernel<<<256, 1024, 0, stream>>>(
          rows + (size_t)(2 * g) * E, cols + (size_t)(2 * g) * E, vals + (size_t)(2 * g) * E,
          H2, cursor, gbuf, out, E, chunk, rounds);
      if (g == 3)
        accum2d_kernel<true><<<NBUCK, 1024, 0, stream>>>(gbuf, cursor, H2, out);
      else
        accum2d_kernel<false><<<NBUCK, 1024, 0, stream>>>(gbuf, cursor, H2, out);
    }
    return;
  }

  // ---- fallback: cast + per-relation gemm + atomic spmm (R0/R2-validated) ----
  uint16_t* X16 = (uint16_t*)ws;                        // 25,600,000
  uint16_t* VtF = (uint16_t*)(ws + 25600000);           //    262,144
  uint16_t* H16 = (uint16_t*)(ws + 25862144);           // 25,600,000
  cast_bf16_kernel<<<(NN * DD / 4 + 255) / 256, 256, 0, stream>>>(features, X16, NN * DD / 4);
  vt_kernel<<<NS * OO, DD, 0, stream>>>(W, Wc, VtF);
  for (int s = 0; s < NS; ++s){
    gemm_kernel<<<(NN + 63) / 64, 256, 0, stream>>>(X16, VtF + (size_t)s * DD * OO, H16);
    spmm_kernel<<<4096, 256, 0, stream>>>(rows + (size_t)s * E, cols + (size_t)s * E,
                                          vals + (size_t)s * E, H16, out, E);
  }
  relu_kernel<<<(NN * OO / 4 + 255) / 256, 256, 0, stream>>>(out, NN * OO / 4);
}

// Round 11
// 1007.369 us; speedup vs baseline: 11.1228x; 1.0265x over previous
//
#include <hip/hip_runtime.h>
#include <hip/hip_bf16.h>
#include <stdint.h>

#define NN 100000   // nodes
#define DD 128      // input dim
#define OO 128      // output dim
#define NS 8        // relations
#define NB 4        // bases

#define BROWS 128   // rows per bucket
#define NBUCK 782   // ceil(NN/BROWS)
#define SDEPTH 16   // bin LDS staging depth per bucket (flush = 16 entries = 128B line)
#define BCAP 4608   // per-bucket capacity for a 2-relation group (mean 4092 + 8 sigma)
#define CPAD 16     // cursor padding (ints) = 64B per counter

typedef __attribute__((ext_vector_type(8))) short short8;
typedef __attribute__((ext_vector_type(4))) float f32x4;

__device__ __forceinline__ float bf2f(uint16_t u){
  union { uint32_t i; float f; } x; x.i = ((uint32_t)u) << 16; return x.f;
}
__device__ __forceinline__ uint16_t f2bf(float f){
  union { float f; uint32_t i; } x; x.f = f;
  uint32_t r = (x.i + 0x7FFFu + ((x.i >> 16) & 1u)) >> 16;  // RNE
  return (uint16_t)r;
}

// ---- effective per-relation weight, TRANSPOSED: Vt[s][o][d] = M_s[d][o] ----
// M_s[d,o] = sum_b W_comp[d&7, b] * W[b*128 + s*16 + (d>>3), o]  (validated R1-R10)
__global__ void vt_kernel(const float* __restrict__ W, const float* __restrict__ Wc,
                          uint16_t* __restrict__ Vt){
  int d  = threadIdx.x;
  int so = blockIdx.x;
  int s = so >> 7, o = so & 127;
  int wrow = s * 16 + (d >> 3);
  int wci  = (d & 7) * NB;
  float acc = 0.f;
#pragma unroll
  for (int b = 0; b < NB; ++b)
    acc += Wc[wci + b] * W[(b * DD + wrow) * OO + o];
  Vt[so * DD + d] = f2bf(acc);
}

// ---- gemm2: H_{s0}, H_{s0+1} = X @ M; reads f32 X once, casts in-register (R10-validated) ----
__global__ __launch_bounds__(256) void gemm2_kernel(const float* __restrict__ X,
                                                    const uint16_t* __restrict__ Vt2,
                                                    uint16_t* __restrict__ H2){
  const int wave = threadIdx.x >> 6;
  const int lane = threadIdx.x & 63;
  const int lr = lane & 15, lk = lane >> 4;
  const int row0 = blockIdx.x * 64 + wave * 16;

  int arow = row0 + lr; if (arow >= NN) arow = NN - 1;
  const float* ap = X + (size_t)arow * DD;
  short8 a[4];
#pragma unroll
  for (int kb = 0; kb < 4; ++kb){
    float4 f0 = *(const float4*)(ap + kb * 32 + lk * 8);
    float4 f1 = *(const float4*)(ap + kb * 32 + lk * 8 + 4);
    short8 t;
    t[0] = (short)f2bf(f0.x); t[1] = (short)f2bf(f0.y);
    t[2] = (short)f2bf(f0.z); t[3] = (short)f2bf(f0.w);
    t[4] = (short)f2bf(f1.x); t[5] = (short)f2bf(f1.y);
    t[6] = (short)f2bf(f1.z); t[7] = (short)f2bf(f1.w);
    a[kb] = t;
  }

  for (int j = 0; j < 2; ++j){
    f32x4 acc[8];
#pragma unroll
    for (int t = 0; t < 8; ++t) acc[t] = (f32x4){0.f, 0.f, 0.f, 0.f};
    const uint16_t* vb = Vt2 + (size_t)j * OO * DD;
#pragma unroll
    for (int kb = 0; kb < 4; ++kb){
#pragma unroll
      for (int t = 0; t < 8; ++t){
        short8 b = *(const short8*)(vb + (size_t)(t * 16 + lr) * DD + kb * 32 + lk * 8);
        acc[t] = __builtin_amdgcn_mfma_f32_16x16x32_bf16(a[kb], b, acc[t], 0, 0, 0);
      }
    }
    uint16_t* hs = H2 + (size_t)j * NN * OO;
#pragma unroll
    for (int t = 0; t < 8; ++t){
#pragma unroll
      for (int jj = 0; jj < 4; ++jj){
        int r = row0 + lk * 4 + jj;
        if (r < NN) hs[(size_t)r * OO + t * 16 + lr] = f2bf(acc[t][jj]);
      }
    }
  }
}

// overflow entry decode: rl[0:6], col[7:23], s[24]
__device__ __noinline__ void overflow_add(int r, int c, int srel, float v,
                                          const uint16_t* __restrict__ H2,
                                          float* __restrict__ out){
  const uint16_t* h = H2 + (size_t)srel * NN * OO + (size_t)c * OO;
  float* dst = out + (size_t)r * OO;
  for (int d = 0; d < OO; ++d) unsafeAtomicAdd(dst + d, v * bf2f(h[d]));
}

// ---- bin3: multisplit 2 relations' edges into row-buckets; 2 edges/thread/round ----
__global__ __launch_bounds__(1024) void bin3_kernel(const int* __restrict__ rows2,
                                                    const int* __restrict__ cols2,
                                                    const float* __restrict__ vals2,
                                                    const uint16_t* __restrict__ H2,
                                                    int* __restrict__ cursor,
                                                    uint2* __restrict__ gbuf,
                                                    float* __restrict__ out,
                                                    int E, int chunk, int rounds){
  __shared__ uint2 stage[NBUCK][SDEPTH];   // 100,096 B
  __shared__ int   scnt[NBUCK];            //   3,128 B
  const int tid = threadIdx.x;
  const int E2 = 2 * E;
  for (int i = tid; i < NBUCK; i += 1024) scnt[i] = 0;
  __syncthreads();
  const int e0 = blockIdx.x * chunk;
  for (int rd = 0; rd < rounds; ++rd){
    int r2[2], c2[2]; float v2[2]; uint32_t sr2[2]; bool ok[2];
#pragma unroll
    for (int k = 0; k < 2; ++k){
      int idx = rd * 2048 + k * 1024 + tid;
      int e = e0 + idx;
      ok[k] = (idx < chunk && e < E2);
      if (ok[k]){
        r2[k] = rows2[e]; c2[k] = cols2[e]; v2[k] = vals2[e];
        sr2[k] = (e >= E) ? 1u : 0u;
      }
    }
#pragma unroll
    for (int k = 0; k < 2; ++k){
      if (ok[k]){
        int b = r2[k] >> 7;
        uint2 ent = make_uint2((uint32_t)(r2[k] & 127) | ((uint32_t)c2[k] << 7) | (sr2[k] << 24),
                               __float_as_uint(v2[k]));
        int sp = atomicAdd(&scnt[b], 1);
        if (sp < SDEPTH){
          stage[b][sp] = ent;
        } else {
          int pos = atomicAdd(&cursor[b * CPAD], 1);
          if (pos < BCAP) gbuf[(size_t)b * BCAP + pos] = ent;
          else overflow_add(r2[k], c2[k], (int)sr2[k], v2[k], H2, out);
        }
      }
    }
    __syncthreads();
    if (tid < NBUCK){
      int b = tid;
      if (scnt[b] >= SDEPTH){
        int pos = atomicAdd(&cursor[b * CPAD], SDEPTH);
#pragma unroll
        for (int i = 0; i < SDEPTH; ++i){
          uint2 ent = stage[b][i];
          if (pos + i < BCAP) gbuf[(size_t)b * BCAP + pos + i] = ent;
          else overflow_add((b << 7) | (int)(ent.x & 127u), (int)((ent.x >> 7) & 0x1FFFFu),
                            (int)(ent.x >> 24), __uint_as_float(ent.y), H2, out);
        }
        scnt[b] = 0;
      }
    }
    __syncthreads();
  }
  if (tid < NBUCK){
    int b = tid;
    int n = scnt[b]; if (n > SDEPTH) n = SDEPTH;
    if (n > 0){
      int pos = atomicAdd(&cursor[b * CPAD], n);
      for (int i = 0; i < n; ++i){
        uint2 ent = stage[b][i];
        if (pos + i < BCAP) gbuf[(size_t)b * BCAP + pos + i] = ent;
        else overflow_add((b << 7) | (int)(ent.x & 127u), (int)((ent.x >> 7) & 0x1FFFFu),
                          (int)(ent.x >> 24), __uint_as_float(ent.y), H2, out);
      }
    }
  }
}

// ---- accum3: 512 threads, srt-only LDS (38.4KB -> 4 blocks/CU), register gather ----
template<bool LAST>
__global__ __launch_bounds__(512) void accum3_kernel(const uint2* __restrict__ gbuf,
                                                     int* __restrict__ cursor,
                                                     const uint16_t* __restrict__ H2,
                                                     float* __restrict__ out){
  __shared__ uint2 srt[BCAP];     // 36,864 B
  __shared__ int   cnt[BROWS];
  __shared__ int   pos[BROWS];
  __shared__ int   cur[BROWS];
  __shared__ int   entS;
  const int b = blockIdx.x;
  const int row0 = b * BROWS;
  const int tid = threadIdx.x;

  if (tid == 0){
    int e = cursor[b * CPAD]; if (e > BCAP) e = BCAP;
    entS = e;
  }
  if (tid < BROWS) cnt[tid] = 0;
  __syncthreads();
  const int entries = entS;
  if (tid == 0) cursor[b * CPAD] = 0;          // re-zero for next group (entS latched)
  const uint2* bbase = gbuf + (size_t)b * BCAP;

  // histogram (gbuf read 1; L2-warm for read 2)
  for (int i = tid; i < entries; i += 512)
    atomicAdd(&cnt[bbase[i].x & 127u], 1);
  __syncthreads();

  // exclusive prefix over 128 counts: wave 0, 2 counts/lane, shfl scan
  if (tid < 64){
    int a  = cnt[2 * tid];
    int c2 = cnt[2 * tid + 1];
    int s  = a + c2;
#pragma unroll
    for (int d = 1; d < 64; d <<= 1){
      int t = __shfl_up(s, d);
      if (tid >= d) s += t;
    }
    int excl = s - (a + c2);
    pos[2 * tid]     = excl;
    pos[2 * tid + 1] = excl + a;
    cur[2 * tid]     = excl;
    cur[2 * tid + 1] = excl + a;
  }
  __syncthreads();

  // reorder into row-sorted LDS (gbuf read 2)
  for (int i = tid; i < entries; i += 512){
    uint2 e = bbase[i];
    int p = atomicAdd(&cur[e.x & 127u], 1);
    srt[p] = e;
  }
  __syncthreads();

  // process: 8 waves x 16 rows; register float2 accumulation; one RMW of out per row
  const int wave = tid >> 6, lane = tid & 63;
#pragma unroll
  for (int rr = 0; rr < 16; ++rr){
    int rl = wave * 16 + rr;
    int row = row0 + rl;
    if (row >= NN) break;
    int n  = cnt[rl];
    int b0 = pos[rl];
    float2 acc = *(const float2*)(out + (size_t)row * OO + lane * 2);
    int k = 0;
    for (; k + 8 <= n; k += 8){
      float accx = 0.f, accy = 0.f;
#pragma unroll
      for (int j = 0; j < 8; ++j){
        uint2 e = srt[b0 + k + j];
        const uint16_t* h = H2 + (size_t)(e.x >> 24) * (NN * OO)
                               + (size_t)((e.x >> 7) & 0x1FFFFu) * OO;
        uint32_t q = ((const uint32_t*)h)[lane];
        float v = __uint_as_float(e.y);
        accx += v * bf2f((uint16_t)(q & 0xFFFFu));
        accy += v * bf2f((uint16_t)(q >> 16));
      }
      acc.x += accx; acc.y += accy;
    }
    for (; k < n; ++k){
      uint2 e = srt[b0 + k];
      const uint16_t* h = H2 + (size_t)(e.x >> 24) * (NN * OO)
                             + (size_t)((e.x >> 7) & 0x1FFFFu) * OO;
      uint32_t q = ((const uint32_t*)h)[lane];
      float v = __uint_as_float(e.y);
      acc.x += v * bf2f((uint16_t)(q & 0xFFFFu));
      acc.y += v * bf2f((uint16_t)(q >> 16));
    }
    if (LAST){ acc.x = fmaxf(acc.x, 0.f); acc.y = fmaxf(acc.y, 0.f); }
    *(float2*)(out + (size_t)row * OO + lane * 2) = acc;
  }
}

// ======== fallback (R0/R2-validated path pieces, only if ws too small) ========
__global__ void cast_bf16_kernel(const float* __restrict__ in, uint16_t* __restrict__ out, int n4){
  int i = blockIdx.x * blockDim.x + threadIdx.x;
  if (i < n4){
    float4 v = ((const float4*)in)[i];
    ushort4 o;
    o.x = f2bf(v.x); o.y = f2bf(v.y); o.z = f2bf(v.z); o.w = f2bf(v.w);
    ((ushort4*)out)[i] = o;
  }
}

__global__ __launch_bounds__(256) void gemm_kernel(const uint16_t* __restrict__ X16,
                                                   const uint16_t* __restrict__ VtS,
                                                   uint16_t* __restrict__ H16){
  const int wave = threadIdx.x >> 6;
  const int lane = threadIdx.x & 63;
  const int lr = lane & 15, lk = lane >> 4;
  const int row0 = blockIdx.x * 64 + wave * 16;
  f32x4 acc[8];
#pragma unroll
  for (int t = 0; t < 8; ++t) acc[t] = (f32x4){0.f, 0.f, 0.f, 0.f};
  int arow = row0 + lr; if (arow >= NN) arow = NN - 1;
  const uint16_t* aptr = X16 + (size_t)arow * DD + lk * 8;
#pragma unroll
  for (int kb = 0; kb < DD; kb += 32){
    short8 a = *(const short8*)(aptr + kb);
#pragma unroll
    for (int t = 0; t < 8; ++t){
      short8 b = *(const short8*)(VtS + (size_t)(t * 16 + lr) * DD + kb + lk * 8);
      acc[t] = __builtin_amdgcn_mfma_f32_16x16x32_bf16(a, b, acc[t], 0, 0, 0);
    }
  }
#pragma unroll
  for (int t = 0; t < 8; ++t){
#pragma unroll
    for (int j = 0; j < 4; ++j){
      int r = row0 + lk * 4 + j;
      if (r < NN) H16[(size_t)r * OO + t * 16 + lr] = f2bf(acc[t][j]);
    }
  }
}

__global__ __launch_bounds__(256) void spmm_kernel(const int* __restrict__ rows,
                                                   const int* __restrict__ cols,
                                                   const float* __restrict__ vals,
                                                   const uint16_t* __restrict__ H16,
                                                   float* __restrict__ out, int E){
  const int lane = threadIdx.x & 63;
  const int gwave = (int)((blockIdx.x * blockDim.x + threadIdx.x) >> 6);
  const int nw = (gridDim.x * blockDim.x) >> 6;
  for (int base = gwave * 64; base < E; base += nw * 64){
    int cnt = E - base; if (cnt > 64) cnt = 64;
    int r = 0, c = 0; float v = 0.f;
    if (lane < cnt){
      r = rows[base + lane]; c = cols[base + lane]; v = vals[base + lane];
    }
    for (int k = 0; k < cnt; ++k){
      int rr = __shfl(r, k);
      int cc = __shfl(c, k);
      float vv = __shfl(v, k);
      uint32_t pair = *(const uint32_t*)(H16 + (size_t)cc * OO + lane * 2);
      float* dst = out + (size_t)rr * OO + lane * 2;
      unsafeAtomicAdd(dst,     vv * bf2f((uint16_t)(pair & 0xFFFFu)));
      unsafeAtomicAdd(dst + 1, vv * bf2f((uint16_t)(pair >> 16)));
    }
  }
}

__global__ void relu_kernel(float* __restrict__ out, int n4){
  int i = blockIdx.x * blockDim.x + threadIdx.x;
  if (i < n4){
    float4 v = ((float4*)out)[i];
    v.x = fmaxf(v.x, 0.f); v.y = fmaxf(v.y, 0.f);
    v.z = fmaxf(v.z, 0.f); v.w = fmaxf(v.w, 0.f);
    ((float4*)out)[i] = v;
  }
}
// =============================================================================

extern "C" void kernel_launch(void* const* d_in, const int* in_sizes, int n_in,
                              void* d_out, int out_size, void* d_ws, size_t ws_size,
                              hipStream_t stream){
  const float* features = (const float*)d_in[0];
  const int*   rows     = (const int*)d_in[1];
  const int*   cols     = (const int*)d_in[2];
  const float* vals     = (const float*)d_in[3];
  const float* W        = (const float*)d_in[4];
  const float* Wc       = (const float*)d_in[5];
  float* out = (float*)d_out;
  const int E = in_sizes[1] / NS;

  char* ws = (char*)d_ws;
  // ---- main layout ----
  uint16_t* Vt     = (uint16_t*)ws;                     //    262,144
  uint16_t* H2     = (uint16_t*)(ws + 262144);          // 51,200,000 (2 relations)
  int*      cursor = (int*)     (ws + 51462144);        //     50,048
  uint2*    gbuf   = (uint2*)   (ws + 51512192);        // 28,827,648 (782 x 4608 x 8B)
  const size_t NEEDED = 51512192 + (size_t)NBUCK * BCAP * 8;   // 80,339,840 < proven ws >= 90,262,144

  hipMemsetAsync(d_out, 0, (size_t)out_size * sizeof(float), stream);

  if (ws_size >= NEEDED){
    vt_kernel<<<NS * OO, DD, 0, stream>>>(W, Wc, Vt);
    hipMemsetAsync(cursor, 0, (size_t)NBUCK * CPAD * sizeof(int), stream);  // once; accum re-zeroes
    const int chunk  = (2 * E + 255) / 256;
    const int rounds = (chunk + 2047) / 2048;
    for (int g = 0; g < 4; ++g){
      gemm2_kernel<<<(NN + 63) / 64, 256, 0, stream>>>(
          features, Vt + (size_t)(2 * g) * OO * DD, H2);
      bin3_kernel<<<256, 1024, 0, stream>>>(
          rows + (size_t)(2 * g) * E, cols + (size_t)(2 * g) * E, vals + (size_t)(2 * g) * E,
          H2, cursor, gbuf, out, E, chunk, rounds);
      if (g == 3)
        accum3_kernel<true><<<NBUCK, 512, 0, stream>>>(gbuf, cursor, H2, out);
      else
        accum3_kernel<false><<<NBUCK, 512, 0, stream>>>(gbuf, cursor, H2, out);
    }
    return;
  }

  // ---- fallback: cast + per-relation gemm + atomic spmm (R0/R2-validated) ----
  uint16_t* X16 = (uint16_t*)ws;                        // 25,600,000
  uint16_t* VtF = (uint16_t*)(ws + 25600000);           //    262,144
  uint16_t* H16 = (uint16_t*)(ws + 25862144);           // 25,600,000
  cast_bf16_kernel<<<(NN * DD / 4 + 255) / 256, 256, 0, stream>>>(features, X16, NN * DD / 4);
  vt_kernel<<<NS * OO, DD, 0, stream>>>(W, Wc, VtF);
  for (int s = 0; s < NS; ++s){
    gemm_kernel<<<(NN + 63) / 64, 256, 0, stream>>>(X16, VtF + (size_t)s * DD * OO, H16);
    spmm_kernel<<<4096, 256, 0, stream>>>(rows + (size_t)s * E, cols + (size_t)s * E,
                                          vals + (size_t)s * E, H16, out, E);
  }
  relu_kernel<<<(NN * OO / 4 + 255) / 256, 256, 0, stream>>>(out, NN * OO / 4);
}